// Round 13
// baseline (662.435 us; speedup 1.0000x reference)
//
#include <hip/hip_runtime.h>
#include <hip/hip_bf16.h>

#define NNODES 100000
#define NPR 12500          // nodes per dst-range (8 ranges)
#define SCAP 262144        // per-range staging capacity

typedef short s16x8 __attribute__((ext_vector_type(8)));
typedef float f32x4 __attribute__((ext_vector_type(4)));
typedef unsigned long long u64;

__device__ inline ushort f2bf(float f) {   // round-to-nearest-even
    uint u = __float_as_uint(f);
    uint r = u + 0x7fffu + ((u >> 16) & 1u);
    return (ushort)(r >> 16);
}
__device__ inline float bf2f(ushort u) { return __uint_as_float(((uint)u) << 16); }
__device__ inline float bflo(uint u) { return __uint_as_float(u << 16); }
__device__ inline float bfhi(uint u) { return __uint_as_float(u & 0xffff0000u); }

// async global->LDS, 16B per lane; lds base wave-uniform (HW: base + lane*16)
__device__ inline void gl_lds16(const ushort* g, ushort* l) {
    __builtin_amdgcn_global_load_lds((const __attribute__((address_space(1))) void*)g,
                                     (__attribute__((address_space(3))) void*)l, 16, 0, 0);
}

// ---------------- CSR build ----------------
// phase 1: bucket edges into 8 per-dst-range lists (coalesced writes)
__global__ __launch_bounds__(256) void bucket_edges(const int* __restrict__ src,
                                                    const int* __restrict__ dst, int E,
                                                    int* __restrict__ rcount,
                                                    u64* __restrict__ stage) {
    __shared__ int cnt[8];
    __shared__ int base[8];
    const int t = threadIdx.x;
    if (t < 8) cnt[t] = 0;
    __syncthreads();
    const int e0 = blockIdx.x * 2048 + t;
    int d[8], s[8], r[8], off[8];
#pragma unroll
    for (int i = 0; i < 8; ++i) {
        int e = e0 + i * 256;
        bool v = e < E;
        int ee = min(e, E - 1);
        d[i] = dst[ee];
        s[i] = src[ee];
        r[i] = d[i] / NPR;
        off[i] = v ? atomicAdd(&cnt[r[i]], 1) : -1;
    }
    __syncthreads();
    if (t < 8) base[t] = atomicAdd(&rcount[t], cnt[t]);
    __syncthreads();
#pragma unroll
    for (int i = 0; i < 8; ++i) {
        if (off[i] >= 0) {
            int slot = base[r[i]] + off[i];
            if (slot < SCAP)
                stage[(size_t)r[i] * SCAP + slot] = ((u64)(uint)d[i] << 32) | (uint)s[i];
        }
    }
}

// XCD-affine histogram over the bucketed lists (atomics confined to a 50 KB window)
__global__ __launch_bounds__(256) void hist_ranged(const u64* __restrict__ stage,
                                                   const int* __restrict__ rcount,
                                                   int* __restrict__ deg) {
    const int r = blockIdx.x & 7;
    const int nb = gridDim.x >> 3;
    const int bi = blockIdx.x >> 3;
    const int cnt = min(rcount[r], SCAP);
    const u64* sp = stage + (size_t)r * SCAP;
    for (int i = bi * 256 + threadIdx.x; i < cnt; i += nb * 256)
        atomicAdd(&deg[(int)(sp[i] >> 32)], 1);
}

__global__ __launch_bounds__(256) void scan_part(const int* __restrict__ deg,
                                                 int* __restrict__ bsum, int n) {
    int t = threadIdx.x;
    int base = blockIdx.x * 1024 + t * 4;
    int4 v = make_int4(0, 0, 0, 0);
    if (base + 3 < n) v = *(const int4*)(deg + base);
    else {
        if (base + 0 < n) v.x = deg[base + 0];
        if (base + 1 < n) v.y = deg[base + 1];
        if (base + 2 < n) v.z = deg[base + 2];
    }
    int s = v.x + v.y + v.z + v.w;
#pragma unroll
    for (int o = 1; o < 64; o <<= 1) s += __shfl_xor(s, o);
    __shared__ int ws[4];
    if ((t & 63) == 0) ws[t >> 6] = s;
    __syncthreads();
    if (t == 0) bsum[blockIdx.x] = ws[0] + ws[1] + ws[2] + ws[3];
}

__global__ __launch_bounds__(128) void scan_bsum(int* __restrict__ bsum, int nb,
                                                 int* __restrict__ rowptr, int n) {
    __shared__ int s[128];
    int t = threadIdx.x;
    int v = (t < nb) ? bsum[t] : 0;
    s[t] = v;
    __syncthreads();
#pragma unroll
    for (int o = 1; o < 128; o <<= 1) {
        int u = (t >= o) ? s[t - o] : 0;
        __syncthreads();
        s[t] += u;
        __syncthreads();
    }
    if (t < nb) bsum[t] = s[t] - v;      // exclusive
    if (t == 127) rowptr[n] = s[127];    // total
}

__global__ __launch_bounds__(256) void scan_apply(const int* __restrict__ deg,
                                                  const int* __restrict__ bsum,
                                                  int* __restrict__ rowptr, int n) {
    int t = threadIdx.x;
    int base = blockIdx.x * 1024 + t * 4;
    int4 v = make_int4(0, 0, 0, 0);
    if (base + 3 < n) v = *(const int4*)(deg + base);
    else {
        if (base + 0 < n) v.x = deg[base + 0];
        if (base + 1 < n) v.y = deg[base + 1];
        if (base + 2 < n) v.z = deg[base + 2];
    }
    int s = v.x + v.y + v.z + v.w;
    int lane = t & 63, w = t >> 6;
    int incl = s;
#pragma unroll
    for (int o = 1; o < 64; o <<= 1) {
        int u = __shfl_up(incl, o);
        if (lane >= o) incl += u;
    }
    __shared__ int wsum[4];
    if (lane == 63) wsum[w] = incl;
    __syncthreads();
    int woff = 0;
    if (w > 0) woff += wsum[0];
    if (w > 1) woff += wsum[1];
    if (w > 2) woff += wsum[2];
    int off = bsum[blockIdx.x] + woff + (incl - s);
    int4 r;
    r.x = off;
    r.y = off + v.x;
    r.z = r.y + v.y;
    r.w = r.z + v.z;
    if (base + 3 < n) *(int4*)(rowptr + base) = r;
    else {
        if (base + 0 < n) rowptr[base + 0] = r.x;
        if (base + 1 < n) rowptr[base + 1] = r.y;
        if (base + 2 < n) rowptr[base + 2] = r.z;
    }
}

// phase 2: XCD-affine scatter (blockIdx&7 selects range -> csr writes stay in one L2)
__global__ __launch_bounds__(256) void scatter_ranged(const u64* __restrict__ stage,
                                                      const int* __restrict__ rcount,
                                                      const int* __restrict__ rowptr,
                                                      int* __restrict__ cursor,
                                                      int* __restrict__ csr) {
    const int r = blockIdx.x & 7;
    const int nb = gridDim.x >> 3;
    const int bi = blockIdx.x >> 3;
    const int cnt = min(rcount[r], SCAP);
    const u64* sp = stage + (size_t)r * SCAP;
    for (int i = bi * 256 + threadIdx.x; i < cnt; i += nb * 256) {
        u64 p = sp[i];
        int d = (int)(p >> 32);
        int s = (int)(uint)p;
        int pos = rowptr[d] + atomicAdd(&cursor[d], 1);
        csr[pos] = s;
    }
}

// ---------------- weight + bias conversion (one kernel) ----------------
struct WConvDesc { const float* W; ushort* Wt; int K, N, Kp; };
struct BCat { const float* src; float* dst; int len; };
struct ConvArgs { WConvDesc d[10]; BCat b[10]; };

__global__ void convert_wb(ConvArgs args) {
    if (blockIdx.y < 10) {
        WConvDesc dd = args.d[blockIdx.y];
        int total = dd.N * dd.Kp;
        for (int i = blockIdx.x * 256 + threadIdx.x; i < total; i += gridDim.x * 256) {
            int n = i / dd.Kp, k = i - n * dd.Kp;
            float v = (k < dd.K) ? dd.W[(size_t)k * dd.N + n] : 0.f;
            dd.Wt[i] = f2bf(v);
        }
    } else if (blockIdx.x < 10) {
        BCat bb = args.b[blockIdx.x];
        for (int i = threadIdx.x; i < bb.len; i += 256) bb.dst[i] = bb.src[i];
    }
}

// ---------------- x conversion: x[M,193] f32 -> xb[M,224] bf16 (padded) ----------------
__global__ void convert_x(const float* __restrict__ x, ushort* __restrict__ xb, int M) {
    int total = M * 56;   // groups of 4 output elems
    for (int i = blockIdx.x * 256 + threadIdx.x; i < total; i += gridDim.x * 256) {
        int n = i / 56;
        int k4 = (i - n * 56) * 4;
        ushort o[4];
#pragma unroll
        for (int j = 0; j < 4; ++j) {
            int k = k4 + j;
            o[j] = (k < 193) ? f2bf(x[(size_t)n * 193 + k]) : (ushort)0;
        }
        *(uint2*)(xb + (size_t)n * 224 + k4) = *(const uint2*)o;
    }
}

// ---------------- MFMA GEMM (bf16 A; double-buffered async staging, counted vmcnt) ----------------
template <int BN>
__global__ __launch_bounds__(256) void gemm_mfma(const ushort* __restrict__ A,
                                                 const ushort* __restrict__ BtAll,
                                                 const float* __restrict__ biasAll,
                                                 ushort* __restrict__ C,
                                                 int M, int Kp, int Cstride,
                                                 int GX, int NPAN) {
    const int id = blockIdx.x;
    const int xcd = id & 7;
    const int jj = id >> 3;
    const int y = jj % NPAN;
    const int xblk = (jj / NPAN) * 8 + xcd;
    if (xblk >= GX) return;
    const int r0 = xblk * 128;
    const int col0 = y * BN;
    const ushort* Bt = BtAll + (size_t)col0 * Kp;
    const float* bias = biasAll + col0;

    __shared__ ushort As[2][128 * 32];
    __shared__ ushort Bs[2][BN * 32];
    const int t = threadIdx.x;
    const int lane = t & 63;
    const int w = t >> 6;
    const int la = lane & 15;
    const int lk = (lane >> 4) * 8;

    constexpr int MR = (BN == 128) ? 4 : 2;
    const int m0 = (BN == 128) ? (w >> 1) * 64 : w * 32;
    const int n0 = (BN == 128) ? (w & 1) * 64 : 0;

    f32x4 acc[MR][4];
#pragma unroll
    for (int i = 0; i < MR; ++i)
#pragma unroll
        for (int j2 = 0; j2 < 4; ++j2) acc[i][j2] = (f32x4)0.f;

    const int lrow4 = lane >> 2;
    const int lkq = (lane & 3) * 8;
    const int arow0 = min(r0 + (2 * w) * 16 + lrow4, M - 1);
    const int arow1 = min(r0 + (2 * w + 1) * 16 + lrow4, M - 1);
    const size_t aoff0 = (size_t)arow0 * Kp + lkq;
    const size_t aoff1 = (size_t)arow1 * Kp + lkq;
    const int brow0 = (BN == 128) ? (2 * w) * 16 + lrow4 : w * 16 + lrow4;
    const int brow1 = (2 * w + 1) * 16 + lrow4;
    const size_t boff0 = (size_t)brow0 * Kp + lkq;
    const size_t boff1 = (size_t)brow1 * Kp + lkq;

    auto STAGE = [&](int b, int k0) {
        gl_lds16(A + aoff0 + k0, &As[b][(2 * w) * 512]);
        gl_lds16(A + aoff1 + k0, &As[b][(2 * w + 1) * 512]);
        if (BN == 128) {
            gl_lds16(Bt + boff0 + k0, &Bs[b][(2 * w) * 512]);
            gl_lds16(Bt + boff1 + k0, &Bs[b][(2 * w + 1) * 512]);
        } else {
            gl_lds16(Bt + boff0 + k0, &Bs[b][w * 512]);
        }
    };

    const int NT = Kp >> 5;
    STAGE(0, 0);
    int cur = 0;
    for (int tt = 0; tt < NT; ++tt) {
        if (tt + 1 < NT) {
            STAGE(cur ^ 1, (tt + 1) * 32);
            if (BN == 128) asm volatile("s_waitcnt vmcnt(4)" ::: "memory");
            else           asm volatile("s_waitcnt vmcnt(3)" ::: "memory");
        } else {
            asm volatile("s_waitcnt vmcnt(0)" ::: "memory");
        }
        __syncthreads();
        s16x8 av[MR], bv[4];
#pragma unroll
        for (int i = 0; i < MR; ++i)
            av[i] = *(const s16x8*)&As[cur][(m0 + i * 16 + la) * 32 + lk];
#pragma unroll
        for (int j2 = 0; j2 < 4; ++j2)
            bv[j2] = *(const s16x8*)&Bs[cur][(n0 + j2 * 16 + la) * 32 + lk];
#pragma unroll
        for (int i = 0; i < MR; ++i)
#pragma unroll
            for (int j2 = 0; j2 < 4; ++j2)
                acc[i][j2] = __builtin_amdgcn_mfma_f32_16x16x32_bf16(av[i], bv[j2], acc[i][j2], 0, 0, 0);
        __syncthreads();
        cur ^= 1;
    }
    const int lrow = (lane >> 4) * 4;
#pragma unroll
    for (int i = 0; i < MR; ++i) {
#pragma unroll
        for (int j2 = 0; j2 < 4; ++j2) {
            int col = n0 + j2 * 16 + la;
            float bval = bias[col];
#pragma unroll
            for (int r = 0; r < 4; ++r) {
                int row = r0 + m0 + i * 16 + lrow + r;
                if (row < M) C[(size_t)row * Cstride + col0 + col] = f2bf(acc[i][j2][r] + bval);
            }
        }
    }
}

// ---------------- GATv2 aggregation (HC=128): one wave/node, 16B gathers, 4-deep pipeline ----------------
__global__ __launch_bounds__(256) void gat_agg128(const ushort* __restrict__ xcat, int xstride,
                                                  int xr_off,
                                                  const ushort* __restrict__ res, int rstride, int roff,
                                                  const float* __restrict__ att,
                                                  const float* __restrict__ bias,
                                                  const int* __restrict__ rowptr,
                                                  const int* __restrict__ csr,
                                                  ushort* __restrict__ houtb, int M) {
    const int n = blockIdx.x * 4 + (threadIdx.x >> 6);
    if (n >= M) return;
    const int lane = threadIdx.x & 63;
    const int clane = lane & 15;
    const int q = lane >> 4;

    const char* xb = (const char*)xcat;
    const uint xrowB = (uint)xstride * 2u;
    const uint chB = (uint)clane * 16u;

    float xr[8], at[8];
    {
        uint4 u = *(const uint4*)(xb + (uint)n * xrowB + (uint)xr_off * 2u + chB);
        xr[0] = bflo(u.x); xr[1] = bfhi(u.x); xr[2] = bflo(u.y); xr[3] = bfhi(u.y);
        xr[4] = bflo(u.z); xr[5] = bfhi(u.z); xr[6] = bflo(u.w); xr[7] = bfhi(u.w);
        const float L2E = 1.4426950408889634f;
        float4 a0 = *(const float4*)(att + 8 * clane);
        float4 a1 = *(const float4*)(att + 8 * clane + 4);
        at[0] = a0.x * L2E; at[1] = a0.y * L2E; at[2] = a0.z * L2E; at[3] = a0.w * L2E;
        at[4] = a1.x * L2E; at[5] = a1.y * L2E; at[6] = a1.z * L2E; at[7] = a1.w * L2E;
    }

    const int s0 = rowptr[n], s1 = rowptr[n + 1];
    float ssum = 0.f;
    float acc[8] = {0.f, 0.f, 0.f, 0.f, 0.f, 0.f, 0.f, 0.f};

    if (s1 > s0) {
        const int nq = (s1 - s0 + 3) >> 2;
        auto ISSUE = [&](uint4& buf, bool& val, int p) {
            if (p >= nq) { val = false; buf = make_uint4(0u, 0u, 0u, 0u); return; }
            int g = s0 + p * 4 + q;
            val = g < s1;
            int src = csr[min(g, s1 - 1)];
            buf = *(const uint4*)(xb + (uint)src * xrowB + chB);
        };
        auto COMPUTE = [&](const uint4& buf, bool val) {
            float x[8];
            x[0] = bflo(buf.x); x[1] = bfhi(buf.x); x[2] = bflo(buf.y); x[3] = bfhi(buf.y);
            x[4] = bflo(buf.z); x[5] = bfhi(buf.z); x[6] = bflo(buf.w); x[7] = bfhi(buf.w);
            float prod = 0.f;
#pragma unroll
            for (int j = 0; j < 8; ++j) {
                float v = x[j] + xr[j];
                float l = fmaxf(v, 0.2f * v);
                prod = fmaf(l, at[j], prod);
            }
            prod += __shfl_xor(prod, 1);
            float pe = val ? exp2f(prod) : 0.f;
            ssum += pe;
#pragma unroll
            for (int j = 0; j < 8; ++j) acc[j] = fmaf(pe, x[j], acc[j]);
        };
        uint4 b0, b1, b2, b3;
        bool v0, v1, v2, v3;
        ISSUE(b0, v0, 0); ISSUE(b1, v1, 1); ISSUE(b2, v2, 2); ISSUE(b3, v3, 3);
        for (int p = 0; p < nq; p += 4) {
            COMPUTE(b0, v0); ISSUE(b0, v0, p + 4);
            if (p + 1 < nq) { COMPUTE(b1, v1); ISSUE(b1, v1, p + 5); }
            if (p + 2 < nq) { COMPUTE(b2, v2); ISSUE(b2, v2, p + 6); }
            if (p + 3 < nq) { COMPUTE(b3, v3); ISSUE(b3, v3, p + 7); }
        }
    }

#pragma unroll
    for (int o = 16; o < 64; o <<= 1) {
        ssum += __shfl_xor(ssum, o);
#pragma unroll
        for (int j = 0; j < 8; ++j) acc[j] += __shfl_xor(acc[j], o);
    }

    float inv = 1.f / (ssum + 1e-16f);
    int ch = 8 * clane + 2 * q;
    float a0s = (q == 0) ? acc[0] : (q == 1) ? acc[2] : (q == 2) ? acc[4] : acc[6];
    float a1s = (q == 0) ? acc[1] : (q == 1) ? acc[3] : (q == 2) ? acc[5] : acc[7];
    uint u = *(const uint*)(res + (size_t)n * rstride + roff + ch);
    float r0v = bflo(u), r1v = bfhi(u);
    float2 b2 = *(const float2*)(bias + ch);
    float y0 = fmaf(a0s, inv, b2.x + r0v);
    float y1 = fmaf(a1s, inv, b2.y + r1v);
    float o0 = 0.5f * y0 * (1.f + erff(y0 * 0.70710678118654752f));
    float o1 = 0.5f * y1 * (1.f + erff(y1 * 0.70710678118654752f));
    *(uint*)(houtb + (size_t)n * 128 + ch) = (uint)f2bf(o0) | ((uint)f2bf(o1) << 16);
}

// ---------------- layer-4 agg (HC=64) with fused 64->32 final linear ----------------
__global__ __launch_bounds__(256) void gat_agg64_lin(const ushort* __restrict__ xcat, int xstride,
                                                     int xr_off,
                                                     const ushort* __restrict__ res, int rstride, int roff,
                                                     const float* __restrict__ att,
                                                     const float* __restrict__ bias,
                                                     const int* __restrict__ rowptr,
                                                     const int* __restrict__ csr,
                                                     const float* __restrict__ linW,
                                                     const float* __restrict__ linb,
                                                     float* __restrict__ out, int M) {
    __shared__ float Ws[64 * 32];
    __shared__ float hs[4][64];
    {
        int t = threadIdx.x;
#pragma unroll
        for (int i = 0; i < 8; ++i) Ws[t + 256 * i] = linW[t + 256 * i];
    }
    __syncthreads();

    const int wid = threadIdx.x >> 6;
    const int n = blockIdx.x * 4 + wid;
    if (n >= M) return;
    const int lane = threadIdx.x & 63;
    const int clane = lane & 7;
    const int q = lane >> 3;

    const char* xb = (const char*)xcat;
    const uint xrowB = (uint)xstride * 2u;
    const uint chB = (uint)clane * 16u;

    float xr[8], at[8];
    {
        uint4 u = *(const uint4*)(xb + (uint)n * xrowB + (uint)xr_off * 2u + chB);
        xr[0] = bflo(u.x); xr[1] = bfhi(u.x); xr[2] = bflo(u.y); xr[3] = bfhi(u.y);
        xr[4] = bflo(u.z); xr[5] = bfhi(u.z); xr[6] = bflo(u.w); xr[7] = bfhi(u.w);
        const float L2E = 1.4426950408889634f;
        float4 a0 = *(const float4*)(att + 8 * clane);
        float4 a1 = *(const float4*)(att + 8 * clane + 4);
        at[0] = a0.x * L2E; at[1] = a0.y * L2E; at[2] = a0.z * L2E; at[3] = a0.w * L2E;
        at[4] = a1.x * L2E; at[5] = a1.y * L2E; at[6] = a1.z * L2E; at[7] = a1.w * L2E;
    }

    const int s0 = rowptr[n], s1 = rowptr[n + 1];
    float ssum = 0.f;
    float acc[8] = {0.f, 0.f, 0.f, 0.f, 0.f, 0.f, 0.f, 0.f};

    if (s1 > s0) {
        const int nq = (s1 - s0 + 7) >> 3;
        auto ISSUE = [&](uint4& buf, bool& val, int p) {
            if (p >= nq) { val = false; buf = make_uint4(0u, 0u, 0u, 0u); return; }
            int g = s0 + p * 8 + q;
            val = g < s1;
            int src = csr[min(g, s1 - 1)];
            buf = *(const uint4*)(xb + (uint)src * xrowB + chB);
        };
        auto COMPUTE = [&](const uint4& buf, bool val) {
            float x[8];
            x[0] = bflo(buf.x); x[1] = bfhi(buf.x); x[2] = bflo(buf.y); x[3] = bfhi(buf.y);
            x[4] = bflo(buf.z); x[5] = bfhi(buf.z); x[6] = bflo(buf.w); x[7] = bfhi(buf.w);
            float prod = 0.f;
#pragma unroll
            for (int j = 0; j < 8; ++j) {
                float v = x[j] + xr[j];
                float l = fmaxf(v, 0.2f * v);
                prod = fmaf(l, at[j], prod);
            }
            float pe = val ? exp2f(prod) : 0.f;
            ssum += pe;
#pragma unroll
            for (int j = 0; j < 8; ++j) acc[j] = fmaf(pe, x[j], acc[j]);
        };
        uint4 b0, b1, b2, b3;
        bool v0, v1, v2, v3;
        ISSUE(b0, v0, 0); ISSUE(b1, v1, 1); ISSUE(b2, v2, 2); ISSUE(b3, v3, 3);
        for (int p = 0; p < nq; p += 4) {
            COMPUTE(b0, v0); ISSUE(b0, v0, p + 4);
            if (p + 1 < nq) { COMPUTE(b1, v1); ISSUE(b1, v1, p + 5); }
            if (p + 2 < nq) { COMPUTE(b2, v2); ISSUE(b2, v2, p + 6); }
            if (p + 3 < nq) { COMPUTE(b3, v3); ISSUE(b3, v3, p + 7); }
        }
    }

#pragma unroll
    for (int o = 8; o < 64; o <<= 1) {
        ssum += __shfl_xor(ssum, o);
#pragma unroll
        for (int j = 0; j < 8; ++j) acc[j] += __shfl_xor(acc[j], o);
    }

    float inv = 1.f / (ssum + 1e-16f);
    int ch = 8 * clane + q;
    float a0s = (q == 0) ? acc[0] : (q == 1) ? acc[1] : (q == 2) ? acc[2] : (q == 3) ? acc[3]
              : (q == 4) ? acc[4] : (q == 5) ? acc[5] : (q == 6) ? acc[6] : acc[7];
    float r0v = bf2f(res[(size_t)n * rstride + roff + ch]);
    float y0 = fmaf(a0s, inv, bias[ch] + r0v);
    float o0 = 0.5f * y0 * (1.f + erff(y0 * 0.70710678118654752f));

    hs[wid][ch] = o0;
    asm volatile("s_waitcnt lgkmcnt(0)" ::: "memory");
    const int col = lane & 31;
    const int half = lane >> 5;
    const float* hp = &hs[wid][half * 32];
    const float* wp = &Ws[(half * 32) * 32 + col];
    float a = 0.f;
#pragma unroll
    for (int k = 0; k < 32; ++k) a = fmaf(hp[k], wp[k * 32], a);
    a += __shfl_xor(a, 32);
    if (half == 0) out[(size_t)n * 32 + col] = a + linb[col];
}

extern "C" void kernel_launch(void* const* d_in, const int* in_sizes, int n_in,
                              void* d_out, int out_size, void* d_ws, size_t ws_size,
                              hipStream_t stream) {
    const float* x = (const float*)d_in[0];
    const int* ei = (const int*)d_in[1];
    const int E = in_sizes[1] / 2;
    const int* srcp = ei;
    const int* dstp = ei + E;

    const float* Wl[4]  = {(const float*)d_in[2],  (const float*)d_in[8],  (const float*)d_in[14], (const float*)d_in[20]};
    const float* bl[4]  = {(const float*)d_in[3],  (const float*)d_in[9],  (const float*)d_in[15], (const float*)d_in[21]};
    const float* Wr[4]  = {(const float*)d_in[4],  (const float*)d_in[10], (const float*)d_in[16], (const float*)d_in[22]};
    const float* br[4]  = {(const float*)d_in[5],  (const float*)d_in[11], (const float*)d_in[17], (const float*)d_in[23]};
    const float* att[4] = {(const float*)d_in[6],  (const float*)d_in[12], (const float*)d_in[18], (const float*)d_in[24]};
    const float* bia[4] = {(const float*)d_in[7],  (const float*)d_in[13], (const float*)d_in[19], (const float*)d_in[25]};
    const float* proj1W = (const float*)d_in[26];
    const float* proj1b = (const float*)d_in[27];
    const float* proj4W = (const float*)d_in[28];
    const float* proj4b = (const float*)d_in[29];
    const float* linW   = (const float*)d_in[30];
    const float* linb   = (const float*)d_in[31];

    const int M = NNODES;
    // ---- workspace layout (xb aliases hb1: x dead after layer-1 GEMM) ----
    ushort* xcat = (ushort*)d_ws;                         // [M,384] bf16 max
    ushort* xb   = xcat + (size_t)M * 384;                // [M,224] bf16 (x padded)
    ushort* hb1  = xb;                                    // alias
    ushort* hb2  = xb + (size_t)M * 224;                  // [M,128] bf16
    ushort* wb = hb2 + (size_t)M * 128;
    ushort* WtC1 = wb; wb += 384 * 224;
    ushort* WtC2 = wb; wb += 256 * 128;
    ushort* WtC3 = wb; wb += 256 * 128;
    ushort* WtC4 = wb; wb += 192 * 128;
    float* bc1 = (float*)wb;
    float* bc2 = bc1 + 384;
    float* bc3 = bc2 + 256;
    float* bc4 = bc3 + 256;
    int* deg    = (int*)(bc4 + 192);
    int* cursor = deg + M;
    int* rcount = cursor + M;            // 8 ints (memset with deg+cursor)
    int* rowptr = rcount + 8;
    int* csr    = rowptr + (M + 1);
    int* bsum   = csr + E;
    u64* stage  = (u64*)(((uintptr_t)(bsum + 128) + 7) & ~(uintptr_t)7);   // 8*SCAP u64

    const int NB = (M + 1023) / 1024;

    // ---- CSR build (bucketed; all random atomics XCD-localized) ----
    hipMemsetAsync(deg, 0, (2 * (size_t)M + 8) * sizeof(int), stream);
    bucket_edges<<<(E + 2047) / 2048, 256, 0, stream>>>(srcp, dstp, E, rcount, stage);
    hist_ranged<<<8 * 96, 256, 0, stream>>>(stage, rcount, deg);
    scan_part<<<NB, 256, 0, stream>>>(deg, bsum, M);
    scan_bsum<<<1, 128, 0, stream>>>(bsum, NB, rowptr, M);
    scan_apply<<<NB, 256, 0, stream>>>(deg, bsum, rowptr, M);
    scatter_ranged<<<8 * 96, 256, 0, stream>>>(stage, rcount, rowptr, cursor, csr);

    // ---- weight + bias + x conversion ----
    ConvArgs ca;
    ca.d[0] = {Wl[0],  WtC1,             193, 128, 224};
    ca.d[1] = {Wr[0],  WtC1 + 128 * 224, 193, 128, 224};
    ca.d[2] = {proj1W, WtC1 + 256 * 224, 193, 128, 224};
    ca.d[3] = {Wl[1],  WtC2,             128, 128, 128};
    ca.d[4] = {Wr[1],  WtC2 + 128 * 128, 128, 128, 128};
    ca.d[5] = {Wl[2],  WtC3,             128, 128, 128};
    ca.d[6] = {Wr[2],  WtC3 + 128 * 128, 128, 128, 128};
    ca.d[7] = {Wl[3],  WtC4,             128, 64, 128};
    ca.d[8] = {Wr[3],  WtC4 + 64 * 128,  128, 64, 128};
    ca.d[9] = {proj4W, WtC4 + 128 * 128, 128, 64, 128};
    ca.b[0] = {bl[0],  bc1,       128};
    ca.b[1] = {br[0],  bc1 + 128, 128};
    ca.b[2] = {proj1b, bc1 + 256, 128};
    ca.b[3] = {bl[1],  bc2,       128};
    ca.b[4] = {br[1],  bc2 + 128, 128};
    ca.b[5] = {bl[2],  bc3,       128};
    ca.b[6] = {br[2],  bc3 + 128, 128};
    ca.b[7] = {bl[3],  bc4,       64};
    ca.b[8] = {br[3],  bc4 + 64,  64};
    ca.b[9] = {proj4b, bc4 + 128, 64};
    convert_wb<<<dim3(112, 11), 256, 0, stream>>>(ca);
    convert_x<<<2048, 256, 0, stream>>>(x, xb, M);

    const int GX = (M + 127) / 128;
    const int S8 = ((GX + 7) / 8) * 8;
    dim3 ag((M + 3) / 4, 1);

    // ---- layer 1: bf16 A (xb), Kp=224, fused 3x128-col GEMM, dbuf staging ----
    gemm_mfma<128><<<S8 * 3, 256, 0, stream>>>(xb, WtC1, bc1, xcat, M, 224, 384, GX, 3);
    gat_agg128<<<ag, 256, 0, stream>>>(xcat, 384, 128, xcat, 384, 256, att[0], bia[0],
                                       rowptr, csr, hb1, M);
    // ---- layer 2 ----
    gemm_mfma<128><<<S8 * 2, 256, 0, stream>>>(hb1, WtC2, bc2, xcat, M, 128, 256, GX, 2);
    gat_agg128<<<ag, 256, 0, stream>>>(xcat, 256, 128, hb1, 128, 0, att[1], bia[1],
                                       rowptr, csr, hb2, M);
    // ---- layer 3 ----
    gemm_mfma<128><<<S8 * 2, 256, 0, stream>>>(hb2, WtC3, bc3, xcat, M, 128, 256, GX, 2);
    gat_agg128<<<ag, 256, 0, stream>>>(xcat, 256, 128, hb2, 128, 0, att[2], bia[2],
                                       rowptr, csr, hb1, M);
    // ---- layer 4 + fused final linear ----
    gemm_mfma<64><<<S8 * 3, 256, 0, stream>>>(hb1, WtC4, bc4, xcat, M, 128, 192, GX, 3);
    gat_agg64_lin<<<ag, 256, 0, stream>>>(xcat, 192, 64, xcat, 192, 128, att[3], bia[3],
                                          rowptr, csr, linW, linb, (float*)d_out, M);
}

// Round 14
// 638.579 us; speedup vs baseline: 1.0374x; 1.0374x over previous
//
#include <hip/hip_runtime.h>
#include <hip/hip_bf16.h>

#define NNODES 100000
#define NPR 12500          // nodes per dst-range (8 ranges)
#define SCAP 262144        // per-range staging capacity

typedef short s16x8 __attribute__((ext_vector_type(8)));
typedef float f32x4 __attribute__((ext_vector_type(4)));
typedef unsigned long long u64;

__device__ inline ushort f2bf(float f) {   // round-to-nearest-even
    uint u = __float_as_uint(f);
    uint r = u + 0x7fffu + ((u >> 16) & 1u);
    return (ushort)(r >> 16);
}
__device__ inline float bf2f(ushort u) { return __uint_as_float(((uint)u) << 16); }
__device__ inline float bflo(uint u) { return __uint_as_float(u << 16); }
__device__ inline float bfhi(uint u) { return __uint_as_float(u & 0xffff0000u); }

// async global->LDS, 16B per lane; lds base wave-uniform (HW: base + lane*16)
__device__ inline void gl_lds16(const ushort* g, ushort* l) {
    __builtin_amdgcn_global_load_lds((const __attribute__((address_space(1))) void*)g,
                                     (__attribute__((address_space(3))) void*)l, 16, 0, 0);
}

// ---------------- CSR build ----------------
// phase 1: bucket edges into 8 per-dst-range lists (coalesced writes)
__global__ __launch_bounds__(256) void bucket_edges(const int* __restrict__ src,
                                                    const int* __restrict__ dst, int E,
                                                    int* __restrict__ rcount,
                                                    u64* __restrict__ stage) {
    __shared__ int cnt[8];
    __shared__ int base[8];
    const int t = threadIdx.x;
    if (t < 8) cnt[t] = 0;
    __syncthreads();
    const int e0 = blockIdx.x * 2048 + t;
    int d[8], s[8], r[8], off[8];
#pragma unroll
    for (int i = 0; i < 8; ++i) {
        int e = e0 + i * 256;
        bool v = e < E;
        int ee = min(e, E - 1);
        d[i] = dst[ee];
        s[i] = src[ee];
        r[i] = d[i] / NPR;
        off[i] = v ? atomicAdd(&cnt[r[i]], 1) : -1;
    }
    __syncthreads();
    if (t < 8) base[t] = atomicAdd(&rcount[t], cnt[t]);
    __syncthreads();
#pragma unroll
    for (int i = 0; i < 8; ++i) {
        if (off[i] >= 0) {
            int slot = base[r[i]] + off[i];
            if (slot < SCAP)
                stage[(size_t)r[i] * SCAP + slot] = ((u64)(uint)d[i] << 32) | (uint)s[i];
        }
    }
}

// XCD-affine histogram over the bucketed lists (atomics confined to a 50 KB window)
__global__ __launch_bounds__(256) void hist_ranged(const u64* __restrict__ stage,
                                                   const int* __restrict__ rcount,
                                                   int* __restrict__ deg) {
    const int r = blockIdx.x & 7;
    const int nb = gridDim.x >> 3;
    const int bi = blockIdx.x >> 3;
    const int cnt = min(rcount[r], SCAP);
    const u64* sp = stage + (size_t)r * SCAP;
    for (int i = bi * 256 + threadIdx.x; i < cnt; i += nb * 256)
        atomicAdd(&deg[(int)(sp[i] >> 32)], 1);
}

__global__ __launch_bounds__(256) void scan_part(const int* __restrict__ deg,
                                                 int* __restrict__ bsum, int n) {
    int t = threadIdx.x;
    int base = blockIdx.x * 1024 + t * 4;
    int4 v = make_int4(0, 0, 0, 0);
    if (base + 3 < n) v = *(const int4*)(deg + base);
    else {
        if (base + 0 < n) v.x = deg[base + 0];
        if (base + 1 < n) v.y = deg[base + 1];
        if (base + 2 < n) v.z = deg[base + 2];
    }
    int s = v.x + v.y + v.z + v.w;
#pragma unroll
    for (int o = 1; o < 64; o <<= 1) s += __shfl_xor(s, o);
    __shared__ int ws[4];
    if ((t & 63) == 0) ws[t >> 6] = s;
    __syncthreads();
    if (t == 0) bsum[blockIdx.x] = ws[0] + ws[1] + ws[2] + ws[3];
}

__global__ __launch_bounds__(128) void scan_bsum(int* __restrict__ bsum, int nb,
                                                 int* __restrict__ rowptr, int n) {
    __shared__ int s[128];
    int t = threadIdx.x;
    int v = (t < nb) ? bsum[t] : 0;
    s[t] = v;
    __syncthreads();
#pragma unroll
    for (int o = 1; o < 128; o <<= 1) {
        int u = (t >= o) ? s[t - o] : 0;
        __syncthreads();
        s[t] += u;
        __syncthreads();
    }
    if (t < nb) bsum[t] = s[t] - v;      // exclusive
    if (t == 127) rowptr[n] = s[127];    // total
}

__global__ __launch_bounds__(256) void scan_apply(const int* __restrict__ deg,
                                                  const int* __restrict__ bsum,
                                                  int* __restrict__ rowptr, int n) {
    int t = threadIdx.x;
    int base = blockIdx.x * 1024 + t * 4;
    int4 v = make_int4(0, 0, 0, 0);
    if (base + 3 < n) v = *(const int4*)(deg + base);
    else {
        if (base + 0 < n) v.x = deg[base + 0];
        if (base + 1 < n) v.y = deg[base + 1];
        if (base + 2 < n) v.z = deg[base + 2];
    }
    int s = v.x + v.y + v.z + v.w;
    int lane = t & 63, w = t >> 6;
    int incl = s;
#pragma unroll
    for (int o = 1; o < 64; o <<= 1) {
        int u = __shfl_up(incl, o);
        if (lane >= o) incl += u;
    }
    __shared__ int wsum[4];
    if (lane == 63) wsum[w] = incl;
    __syncthreads();
    int woff = 0;
    if (w > 0) woff += wsum[0];
    if (w > 1) woff += wsum[1];
    if (w > 2) woff += wsum[2];
    int off = bsum[blockIdx.x] + woff + (incl - s);
    int4 r;
    r.x = off;
    r.y = off + v.x;
    r.z = r.y + v.y;
    r.w = r.z + v.z;
    if (base + 3 < n) *(int4*)(rowptr + base) = r;
    else {
        if (base + 0 < n) rowptr[base + 0] = r.x;
        if (base + 1 < n) rowptr[base + 1] = r.y;
        if (base + 2 < n) rowptr[base + 2] = r.z;
    }
}

// phase 2: XCD-affine scatter (blockIdx&7 selects range -> csr writes stay in one L2)
__global__ __launch_bounds__(256) void scatter_ranged(const u64* __restrict__ stage,
                                                      const int* __restrict__ rcount,
                                                      const int* __restrict__ rowptr,
                                                      int* __restrict__ cursor,
                                                      int* __restrict__ csr) {
    const int r = blockIdx.x & 7;
    const int nb = gridDim.x >> 3;
    const int bi = blockIdx.x >> 3;
    const int cnt = min(rcount[r], SCAP);
    const u64* sp = stage + (size_t)r * SCAP;
    for (int i = bi * 256 + threadIdx.x; i < cnt; i += nb * 256) {
        u64 p = sp[i];
        int d = (int)(p >> 32);
        int s = (int)(uint)p;
        int pos = rowptr[d] + atomicAdd(&cursor[d], 1);
        csr[pos] = s;
    }
}

// ---------------- weight + bias conversion (one kernel) ----------------
struct WConvDesc { const float* W; ushort* Wt; int K, N, Kp; };
struct BCat { const float* src; float* dst; int len; };
struct ConvArgs { WConvDesc d[10]; BCat b[10]; };

__global__ void convert_wb(ConvArgs args) {
    if (blockIdx.y < 10) {
        WConvDesc dd = args.d[blockIdx.y];
        int total = dd.N * dd.Kp;
        for (int i = blockIdx.x * 256 + threadIdx.x; i < total; i += gridDim.x * 256) {
            int n = i / dd.Kp, k = i - n * dd.Kp;
            float v = (k < dd.K) ? dd.W[(size_t)k * dd.N + n] : 0.f;
            dd.Wt[i] = f2bf(v);
        }
    } else if (blockIdx.x < 10) {
        BCat bb = args.b[blockIdx.x];
        for (int i = threadIdx.x; i < bb.len; i += 256) bb.dst[i] = bb.src[i];
    }
}

// ---------------- x conversion: x[M,193] f32 -> xb[M,224] bf16 (padded) ----------------
__global__ void convert_x(const float* __restrict__ x, ushort* __restrict__ xb, int M) {
    int total = M * 56;   // groups of 4 output elems
    for (int i = blockIdx.x * 256 + threadIdx.x; i < total; i += gridDim.x * 256) {
        int n = i / 56;
        int k4 = (i - n * 56) * 4;
        ushort o[4];
#pragma unroll
        for (int j = 0; j < 4; ++j) {
            int k = k4 + j;
            o[j] = (k < 193) ? f2bf(x[(size_t)n * 193 + k]) : (ushort)0;
        }
        *(uint2*)(xb + (size_t)n * 224 + k4) = *(const uint2*)o;
    }
}

// ---------------- MFMA GEMM (single-buffered global_load_lds staging; XCD panel mapping) ----------------
// R11-proven form: drain (vmcnt(0)) + __syncthreads per K-tile; 16KB LDS -> high occupancy.
template <int BN>
__global__ __launch_bounds__(256) void gemm_mfma(const ushort* __restrict__ A,
                                                 const ushort* __restrict__ BtAll,
                                                 const float* __restrict__ biasAll,
                                                 ushort* __restrict__ C,
                                                 int M, int Kp, int Cstride,
                                                 int GX, int NPAN) {
    const int id = blockIdx.x;
    const int xcd = id & 7;
    const int jj = id >> 3;
    const int y = jj % NPAN;
    const int xblk = (jj / NPAN) * 8 + xcd;
    if (xblk >= GX) return;
    const int r0 = xblk * 128;
    const int col0 = y * BN;
    const ushort* Bt = BtAll + (size_t)col0 * Kp;
    const float* bias = biasAll + col0;

    __shared__ ushort As[128 * 32];   // [row][k], 64 B/row, linear (global_load_lds dest)
    __shared__ ushort Bs[BN * 32];
    const int t = threadIdx.x;
    const int lane = t & 63;
    const int w = t >> 6;
    const int la = lane & 15;
    const int lk = (lane >> 4) * 8;

    constexpr int MR = (BN == 128) ? 4 : 2;
    const int m0 = (BN == 128) ? (w >> 1) * 64 : w * 32;
    const int n0 = (BN == 128) ? (w & 1) * 64 : 0;

    f32x4 acc[MR][4];
#pragma unroll
    for (int i = 0; i < MR; ++i)
#pragma unroll
        for (int j2 = 0; j2 < 4; ++j2) acc[i][j2] = (f32x4)0.f;

    const int lrow4 = lane >> 2;
    const int lkq = (lane & 3) * 8;
    const int arow0 = min(r0 + (2 * w) * 16 + lrow4, M - 1);
    const int arow1 = min(r0 + (2 * w + 1) * 16 + lrow4, M - 1);
    const size_t aoff0 = (size_t)arow0 * Kp + lkq;
    const size_t aoff1 = (size_t)arow1 * Kp + lkq;
    const int brow0 = (BN == 128) ? (2 * w) * 16 + lrow4 : w * 16 + lrow4;
    const int brow1 = (2 * w + 1) * 16 + lrow4;
    const size_t boff0 = (size_t)brow0 * Kp + lkq;
    const size_t boff1 = (size_t)brow1 * Kp + lkq;

    for (int k0 = 0; k0 < Kp; k0 += 32) {
        gl_lds16(A + aoff0 + k0, &As[(2 * w) * 512]);
        gl_lds16(A + aoff1 + k0, &As[(2 * w + 1) * 512]);
        if (BN == 128) {
            gl_lds16(Bt + boff0 + k0, &Bs[(2 * w) * 512]);
            gl_lds16(Bt + boff1 + k0, &Bs[(2 * w + 1) * 512]);
        } else {
            gl_lds16(Bt + boff0 + k0, &Bs[w * 512]);
        }
        asm volatile("s_waitcnt vmcnt(0)" ::: "memory");
        __syncthreads();
        s16x8 av[MR], bv[4];
#pragma unroll
        for (int i = 0; i < MR; ++i)
            av[i] = *(const s16x8*)&As[(m0 + i * 16 + la) * 32 + lk];
#pragma unroll
        for (int j2 = 0; j2 < 4; ++j2)
            bv[j2] = *(const s16x8*)&Bs[(n0 + j2 * 16 + la) * 32 + lk];
#pragma unroll
        for (int i = 0; i < MR; ++i)
#pragma unroll
            for (int j2 = 0; j2 < 4; ++j2)
                acc[i][j2] = __builtin_amdgcn_mfma_f32_16x16x32_bf16(av[i], bv[j2], acc[i][j2], 0, 0, 0);
        __syncthreads();
    }
    const int lrow = (lane >> 4) * 4;
#pragma unroll
    for (int i = 0; i < MR; ++i) {
#pragma unroll
        for (int j2 = 0; j2 < 4; ++j2) {
            int col = n0 + j2 * 16 + la;
            float bval = bias[col];
#pragma unroll
            for (int r = 0; r < 4; ++r) {
                int row = r0 + m0 + i * 16 + lrow + r;
                if (row < M) C[(size_t)row * Cstride + col0 + col] = f2bf(acc[i][j2][r] + bval);
            }
        }
    }
}

// ---------------- GATv2 aggregation (HC=128): one wave/node, 16B gathers, 4-deep pipeline ----------------
__global__ __launch_bounds__(256) void gat_agg128(const ushort* __restrict__ xcat, int xstride,
                                                  int xr_off,
                                                  const ushort* __restrict__ res, int rstride, int roff,
                                                  const float* __restrict__ att,
                                                  const float* __restrict__ bias,
                                                  const int* __restrict__ rowptr,
                                                  const int* __restrict__ csr,
                                                  ushort* __restrict__ houtb, int M) {
    const int n = blockIdx.x * 4 + (threadIdx.x >> 6);
    if (n >= M) return;
    const int lane = threadIdx.x & 63;
    const int clane = lane & 15;
    const int q = lane >> 4;

    const char* xb = (const char*)xcat;
    const uint xrowB = (uint)xstride * 2u;
    const uint chB = (uint)clane * 16u;

    float xr[8], at[8];
    {
        uint4 u = *(const uint4*)(xb + (uint)n * xrowB + (uint)xr_off * 2u + chB);
        xr[0] = bflo(u.x); xr[1] = bfhi(u.x); xr[2] = bflo(u.y); xr[3] = bfhi(u.y);
        xr[4] = bflo(u.z); xr[5] = bfhi(u.z); xr[6] = bflo(u.w); xr[7] = bfhi(u.w);
        const float L2E = 1.4426950408889634f;
        float4 a0 = *(const float4*)(att + 8 * clane);
        float4 a1 = *(const float4*)(att + 8 * clane + 4);
        at[0] = a0.x * L2E; at[1] = a0.y * L2E; at[2] = a0.z * L2E; at[3] = a0.w * L2E;
        at[4] = a1.x * L2E; at[5] = a1.y * L2E; at[6] = a1.z * L2E; at[7] = a1.w * L2E;
    }

    const int s0 = rowptr[n], s1 = rowptr[n + 1];
    float ssum = 0.f;
    float acc[8] = {0.f, 0.f, 0.f, 0.f, 0.f, 0.f, 0.f, 0.f};

    if (s1 > s0) {
        const int nq = (s1 - s0 + 3) >> 2;
        auto ISSUE = [&](uint4& buf, bool& val, int p) {
            if (p >= nq) { val = false; buf = make_uint4(0u, 0u, 0u, 0u); return; }
            int g = s0 + p * 4 + q;
            val = g < s1;
            int src = csr[min(g, s1 - 1)];
            buf = *(const uint4*)(xb + (uint)src * xrowB + chB);
        };
        auto COMPUTE = [&](const uint4& buf, bool val) {
            float x[8];
            x[0] = bflo(buf.x); x[1] = bfhi(buf.x); x[2] = bflo(buf.y); x[3] = bfhi(buf.y);
            x[4] = bflo(buf.z); x[5] = bfhi(buf.z); x[6] = bflo(buf.w); x[7] = bfhi(buf.w);
            float prod = 0.f;
#pragma unroll
            for (int j = 0; j < 8; ++j) {
                float v = x[j] + xr[j];
                float l = fmaxf(v, 0.2f * v);
                prod = fmaf(l, at[j], prod);
            }
            prod += __shfl_xor(prod, 1);
            float pe = val ? exp2f(prod) : 0.f;
            ssum += pe;
#pragma unroll
            for (int j = 0; j < 8; ++j) acc[j] = fmaf(pe, x[j], acc[j]);
        };
        uint4 b0, b1, b2, b3;
        bool v0, v1, v2, v3;
        ISSUE(b0, v0, 0); ISSUE(b1, v1, 1); ISSUE(b2, v2, 2); ISSUE(b3, v3, 3);
        for (int p = 0; p < nq; p += 4) {
            COMPUTE(b0, v0); ISSUE(b0, v0, p + 4);
            if (p + 1 < nq) { COMPUTE(b1, v1); ISSUE(b1, v1, p + 5); }
            if (p + 2 < nq) { COMPUTE(b2, v2); ISSUE(b2, v2, p + 6); }
            if (p + 3 < nq) { COMPUTE(b3, v3); ISSUE(b3, v3, p + 7); }
        }
    }

#pragma unroll
    for (int o = 16; o < 64; o <<= 1) {
        ssum += __shfl_xor(ssum, o);
#pragma unroll
        for (int j = 0; j < 8; ++j) acc[j] += __shfl_xor(acc[j], o);
    }

    float inv = 1.f / (ssum + 1e-16f);
    int ch = 8 * clane + 2 * q;
    float a0s = (q == 0) ? acc[0] : (q == 1) ? acc[2] : (q == 2) ? acc[4] : acc[6];
    float a1s = (q == 0) ? acc[1] : (q == 1) ? acc[3] : (q == 2) ? acc[5] : acc[7];
    uint u = *(const uint*)(res + (size_t)n * rstride + roff + ch);
    float r0v = bflo(u), r1v = bfhi(u);
    float2 b2 = *(const float2*)(bias + ch);
    float y0 = fmaf(a0s, inv, b2.x + r0v);
    float y1 = fmaf(a1s, inv, b2.y + r1v);
    float o0 = 0.5f * y0 * (1.f + erff(y0 * 0.70710678118654752f));
    float o1 = 0.5f * y1 * (1.f + erff(y1 * 0.70710678118654752f));
    *(uint*)(houtb + (size_t)n * 128 + ch) = (uint)f2bf(o0) | ((uint)f2bf(o1) << 16);
}

// ---------------- layer-4 agg (HC=64) with fused 64->32 final linear ----------------
__global__ __launch_bounds__(256) void gat_agg64_lin(const ushort* __restrict__ xcat, int xstride,
                                                     int xr_off,
                                                     const ushort* __restrict__ res, int rstride, int roff,
                                                     const float* __restrict__ att,
                                                     const float* __restrict__ bias,
                                                     const int* __restrict__ rowptr,
                                                     const int* __restrict__ csr,
                                                     const float* __restrict__ linW,
                                                     const float* __restrict__ linb,
                                                     float* __restrict__ out, int M) {
    __shared__ float Ws[64 * 32];
    __shared__ float hs[4][64];
    {
        int t = threadIdx.x;
#pragma unroll
        for (int i = 0; i < 8; ++i) Ws[t + 256 * i] = linW[t + 256 * i];
    }
    __syncthreads();

    const int wid = threadIdx.x >> 6;
    const int n = blockIdx.x * 4 + wid;
    if (n >= M) return;
    const int lane = threadIdx.x & 63;
    const int clane = lane & 7;
    const int q = lane >> 3;

    const char* xb = (const char*)xcat;
    const uint xrowB = (uint)xstride * 2u;
    const uint chB = (uint)clane * 16u;

    float xr[8], at[8];
    {
        uint4 u = *(const uint4*)(xb + (uint)n * xrowB + (uint)xr_off * 2u + chB);
        xr[0] = bflo(u.x); xr[1] = bfhi(u.x); xr[2] = bflo(u.y); xr[3] = bfhi(u.y);
        xr[4] = bflo(u.z); xr[5] = bfhi(u.z); xr[6] = bflo(u.w); xr[7] = bfhi(u.w);
        const float L2E = 1.4426950408889634f;
        float4 a0 = *(const float4*)(att + 8 * clane);
        float4 a1 = *(const float4*)(att + 8 * clane + 4);
        at[0] = a0.x * L2E; at[1] = a0.y * L2E; at[2] = a0.z * L2E; at[3] = a0.w * L2E;
        at[4] = a1.x * L2E; at[5] = a1.y * L2E; at[6] = a1.z * L2E; at[7] = a1.w * L2E;
    }

    const int s0 = rowptr[n], s1 = rowptr[n + 1];
    float ssum = 0.f;
    float acc[8] = {0.f, 0.f, 0.f, 0.f, 0.f, 0.f, 0.f, 0.f};

    if (s1 > s0) {
        const int nq = (s1 - s0 + 7) >> 3;
        auto ISSUE = [&](uint4& buf, bool& val, int p) {
            if (p >= nq) { val = false; buf = make_uint4(0u, 0u, 0u, 0u); return; }
            int g = s0 + p * 8 + q;
            val = g < s1;
            int src = csr[min(g, s1 - 1)];
            buf = *(const uint4*)(xb + (uint)src * xrowB + chB);
        };
        auto COMPUTE = [&](const uint4& buf, bool val) {
            float x[8];
            x[0] = bflo(buf.x); x[1] = bfhi(buf.x); x[2] = bflo(buf.y); x[3] = bfhi(buf.y);
            x[4] = bflo(buf.z); x[5] = bfhi(buf.z); x[6] = bflo(buf.w); x[7] = bfhi(buf.w);
            float prod = 0.f;
#pragma unroll
            for (int j = 0; j < 8; ++j) {
                float v = x[j] + xr[j];
                float l = fmaxf(v, 0.2f * v);
                prod = fmaf(l, at[j], prod);
            }
            float pe = val ? exp2f(prod) : 0.f;
            ssum += pe;
#pragma unroll
            for (int j = 0; j < 8; ++j) acc[j] = fmaf(pe, x[j], acc[j]);
        };
        uint4 b0, b1, b2, b3;
        bool v0, v1, v2, v3;
        ISSUE(b0, v0, 0); ISSUE(b1, v1, 1); ISSUE(b2, v2, 2); ISSUE(b3, v3, 3);
        for (int p = 0; p < nq; p += 4) {
            COMPUTE(b0, v0); ISSUE(b0, v0, p + 4);
            if (p + 1 < nq) { COMPUTE(b1, v1); ISSUE(b1, v1, p + 5); }
            if (p + 2 < nq) { COMPUTE(b2, v2); ISSUE(b2, v2, p + 6); }
            if (p + 3 < nq) { COMPUTE(b3, v3); ISSUE(b3, v3, p + 7); }
        }
    }

#pragma unroll
    for (int o = 8; o < 64; o <<= 1) {
        ssum += __shfl_xor(ssum, o);
#pragma unroll
        for (int j = 0; j < 8; ++j) acc[j] += __shfl_xor(acc[j], o);
    }

    float inv = 1.f / (ssum + 1e-16f);
    int ch = 8 * clane + q;
    float a0s = (q == 0) ? acc[0] : (q == 1) ? acc[1] : (q == 2) ? acc[2] : (q == 3) ? acc[3]
              : (q == 4) ? acc[4] : (q == 5) ? acc[5] : (q == 6) ? acc[6] : acc[7];
    float r0v = bf2f(res[(size_t)n * rstride + roff + ch]);
    float y0 = fmaf(a0s, inv, bias[ch] + r0v);
    float o0 = 0.5f * y0 * (1.f + erff(y0 * 0.70710678118654752f));

    hs[wid][ch] = o0;
    asm volatile("s_waitcnt lgkmcnt(0)" ::: "memory");
    const int col = lane & 31;
    const int half = lane >> 5;
    const float* hp = &hs[wid][half * 32];
    const float* wp = &Ws[(half * 32) * 32 + col];
    float a = 0.f;
#pragma unroll
    for (int k = 0; k < 32; ++k) a = fmaf(hp[k], wp[k * 32], a);
    a += __shfl_xor(a, 32);
    if (half == 0) out[(size_t)n * 32 + col] = a + linb[col];
}

extern "C" void kernel_launch(void* const* d_in, const int* in_sizes, int n_in,
                              void* d_out, int out_size, void* d_ws, size_t ws_size,
                              hipStream_t stream) {
    const float* x = (const float*)d_in[0];
    const int* ei = (const int*)d_in[1];
    const int E = in_sizes[1] / 2;
    const int* srcp = ei;
    const int* dstp = ei + E;

    const float* Wl[4]  = {(const float*)d_in[2],  (const float*)d_in[8],  (const float*)d_in[14], (const float*)d_in[20]};
    const float* bl[4]  = {(const float*)d_in[3],  (const float*)d_in[9],  (const float*)d_in[15], (const float*)d_in[21]};
    const float* Wr[4]  = {(const float*)d_in[4],  (const float*)d_in[10], (const float*)d_in[16], (const float*)d_in[22]};
    const float* br[4]  = {(const float*)d_in[5],  (const float*)d_in[11], (const float*)d_in[17], (const float*)d_in[23]};
    const float* att[4] = {(const float*)d_in[6],  (const float*)d_in[12], (const float*)d_in[18], (const float*)d_in[24]};
    const float* bia[4] = {(const float*)d_in[7],  (const float*)d_in[13], (const float*)d_in[19], (const float*)d_in[25]};
    const float* proj1W = (const float*)d_in[26];
    const float* proj1b = (const float*)d_in[27];
    const float* proj4W = (const float*)d_in[28];
    const float* proj4b = (const float*)d_in[29];
    const float* linW   = (const float*)d_in[30];
    const float* linb   = (const float*)d_in[31];

    const int M = NNODES;
    // ---- workspace layout (xb aliases hb1: x dead after layer-1 GEMM) ----
    ushort* xcat = (ushort*)d_ws;                         // [M,384] bf16 max
    ushort* xb   = xcat + (size_t)M * 384;                // [M,224] bf16 (x padded)
    ushort* hb1  = xb;                                    // alias
    ushort* hb2  = xb + (size_t)M * 224;                  // [M,128] bf16
    ushort* wb = hb2 + (size_t)M * 128;
    ushort* WtC1 = wb; wb += 384 * 224;
    ushort* WtC2 = wb; wb += 256 * 128;
    ushort* WtC3 = wb; wb += 256 * 128;
    ushort* WtC4 = wb; wb += 192 * 128;
    float* bc1 = (float*)wb;
    float* bc2 = bc1 + 384;
    float* bc3 = bc2 + 256;
    float* bc4 = bc3 + 256;
    int* deg    = (int*)(bc4 + 192);
    int* cursor = deg + M;
    int* rcount = cursor + M;            // 8 ints (memset with deg+cursor)
    int* rowptr = rcount + 8;
    int* csr    = rowptr + (M + 1);
    int* bsum   = csr + E;
    u64* stage  = (u64*)(((uintptr_t)(bsum + 128) + 7) & ~(uintptr_t)7);   // 8*SCAP u64

    const int NB = (M + 1023) / 1024;

    // ---- CSR build (bucketed; all random atomics XCD-localized) ----
    hipMemsetAsync(deg, 0, (2 * (size_t)M + 8) * sizeof(int), stream);
    bucket_edges<<<(E + 2047) / 2048, 256, 0, stream>>>(srcp, dstp, E, rcount, stage);
    hist_ranged<<<8 * 96, 256, 0, stream>>>(stage, rcount, deg);
    scan_part<<<NB, 256, 0, stream>>>(deg, bsum, M);
    scan_bsum<<<1, 128, 0, stream>>>(bsum, NB, rowptr, M);
    scan_apply<<<NB, 256, 0, stream>>>(deg, bsum, rowptr, M);
    scatter_ranged<<<8 * 96, 256, 0, stream>>>(stage, rcount, rowptr, cursor, csr);

    // ---- weight + bias + x conversion ----
    ConvArgs ca;
    ca.d[0] = {Wl[0],  WtC1,             193, 128, 224};
    ca.d[1] = {Wr[0],  WtC1 + 128 * 224, 193, 128, 224};
    ca.d[2] = {proj1W, WtC1 + 256 * 224, 193, 128, 224};
    ca.d[3] = {Wl[1],  WtC2,             128, 128, 128};
    ca.d[4] = {Wr[1],  WtC2 + 128 * 128, 128, 128, 128};
    ca.d[5] = {Wl[2],  WtC3,             128, 128, 128};
    ca.d[6] = {Wr[2],  WtC3 + 128 * 128, 128, 128, 128};
    ca.d[7] = {Wl[3],  WtC4,             128, 64, 128};
    ca.d[8] = {Wr[3],  WtC4 + 64 * 128,  128, 64, 128};
    ca.d[9] = {proj4W, WtC4 + 128 * 128, 128, 64, 128};
    ca.b[0] = {bl[0],  bc1,       128};
    ca.b[1] = {br[0],  bc1 + 128, 128};
    ca.b[2] = {proj1b, bc1 + 256, 128};
    ca.b[3] = {bl[1],  bc2,       128};
    ca.b[4] = {br[1],  bc2 + 128, 128};
    ca.b[5] = {bl[2],  bc3,       128};
    ca.b[6] = {br[2],  bc3 + 128, 128};
    ca.b[7] = {bl[3],  bc4,       64};
    ca.b[8] = {br[3],  bc4 + 64,  64};
    ca.b[9] = {proj4b, bc4 + 128, 64};
    convert_wb<<<dim3(112, 11), 256, 0, stream>>>(ca);
    convert_x<<<2048, 256, 0, stream>>>(x, xb, M);

    const int GX = (M + 127) / 128;
    const int S8 = ((GX + 7) / 8) * 8;
    dim3 ag((M + 3) / 4, 1);

    // ---- layer 1: bf16 A (xb), Kp=224, fused 3x128-col GEMM ----
    gemm_mfma<128><<<S8 * 3, 256, 0, stream>>>(xb, WtC1, bc1, xcat, M, 224, 384, GX, 3);
    gat_agg128<<<ag, 256, 0, stream>>>(xcat, 384, 128, xcat, 384, 256, att[0], bia[0],
                                       rowptr, csr, hb1, M);
    // ---- layer 2 ----
    gemm_mfma<128><<<S8 * 2, 256, 0, stream>>>(hb1, WtC2, bc2, xcat, M, 128, 256, GX, 2);
    gat_agg128<<<ag, 256, 0, stream>>>(xcat, 256, 128, hb1, 128, 0, att[1], bia[1],
                                       rowptr, csr, hb2, M);
    // ---- layer 3 ----
    gemm_mfma<128><<<S8 * 2, 256, 0, stream>>>(hb2, WtC3, bc3, xcat, M, 128, 256, GX, 2);
    gat_agg128<<<ag, 256, 0, stream>>>(xcat, 256, 128, hb2, 128, 0, att[2], bia[2],
                                       rowptr, csr, hb1, M);
    // ---- layer 4 + fused final linear ----
    gemm_mfma<64><<<S8 * 3, 256, 0, stream>>>(hb1, WtC4, bc4, xcat, M, 128, 192, GX, 3);
    gat_agg64_lin<<<ag, 256, 0, stream>>>(xcat, 192, 64, xcat, 192, 128, att[3], bia[3],
                                          rowptr, csr, linW, linb, (float*)d_out, M);
}